// Round 7
// baseline (148.534 us; speedup 1.0000x reference)
//
#include <hip/hip_runtime.h>
#include <math.h>

#define D 512
#define NHEADS 8
#define HD 64
#define SEQ 2048
#define BATCH 4
#define MROWS (BATCH*SEQ)
#define QKVSTR 1536
// (1/sqrt(512)) * log2(e): Q pre-scale so softmax runs in exp2 domain
#define ATT_QSCALE 0.06376228841159383f

typedef short bf16x8 __attribute__((ext_vector_type(8)));
typedef float f32x4 __attribute__((ext_vector_type(4)));
typedef float f32x16 __attribute__((ext_vector_type(16)));

__device__ __forceinline__ ushort f2bf(float f) {
    union { float f; unsigned u; } v; v.f = f;
    unsigned r = (v.u + 0x7fffu + ((v.u >> 16) & 1u)) >> 16;
    return (ushort)r;
}
__device__ __forceinline__ float bf2f(ushort u) {
    union { unsigned u; float f; } v; v.u = ((unsigned)u) << 16; return v.f;
}

__device__ __forceinline__ unsigned cvt_pk_bf16(float lo, float hi_) {
    unsigned r;
    asm("v_cvt_pk_bf16_f32 %0, %1, %2" : "=v"(r) : "v"(lo), "v"(hi_));
    return r;
}

// 2^x via the transcendental unit (input already in log2 domain)
__device__ __forceinline__ float exp2_hw(float x) {
    float r;
    asm("v_exp_f32 %0, %1" : "=v"(r) : "v"(x));
    return r;
}
__device__ __forceinline__ float rcp_hw(float x) {
    float r;
    asm("v_rcp_f32 %0, %1" : "=v"(r) : "v"(x));
    return r;
}

// Fast exact-GELU: erf via Abramowitz-Stegun 7.1.26 (|err| <= ~2e-5 with HW
// rcp) on the transcendental unit. Replaced libm erff in R6: up-GEMM left the
// top-5 (~3 us), absmax unchanged.
__device__ __forceinline__ float gelu_fast(float x) {
    const float z = fabsf(x) * 0.70710678118654752f;
    const float t = rcp_hw(fmaf(0.3275911f, z, 1.0f));
    float p = fmaf(1.061405429f, t, -1.453152027f);
    p = fmaf(p, t, 1.421413741f);
    p = fmaf(p, t, -0.284496736f);
    p = fmaf(p, t, 0.254829592f);
    const float e = exp2_hw(-z * z * 1.4426950408889634f);
    const float erfz = 1.0f - p * t * e;        // erf(|x|/sqrt(2))
    const float s = copysignf(erfz, x);
    return 0.5f * x * (1.0f + s);
}

// v_permlane32_swap_b32: swaps the lower 32 lanes of a with upper 32 lanes of b.
__device__ __forceinline__ void plswap(unsigned &a, unsigned &b) {
    asm("v_permlane32_swap_b32 %0, %1" : "+v"(a), "+v"(b));
}
__device__ __forceinline__ void plswapf(float &a, float &b) {
    union { float f; unsigned u; } ua, ub;
    ua.f = a; ub.f = b;
    asm("v_permlane32_swap_b32 %0, %1" : "+v"(ua.u), "+v"(ub.u));
    a = ua.f; b = ub.f;
}

// global -> LDS direct copy, 16B per lane. LDS dest = wave-uniform base + lane*16.
__device__ __forceinline__ void gload16(const void* g, void* lds) {
    __builtin_amdgcn_global_load_lds(
        (const __attribute__((address_space(1))) unsigned int*)(uintptr_t)g,
        (__attribute__((address_space(3))) unsigned int*)(uintptr_t)lds,
        16, 0, 0);
}

// XCD-chunked bijective block swizzle (T1). R4 verified on up-GEMM: FETCH
// 35.5 -> 20.7 MB (8-XCD compulsory floor), dur 53.5 -> 47 us. R5 verified
// on attn: FETCH 69.7 -> 12.3 MB. Requires nwg % 8 == 0.
__device__ __forceinline__ int xcd_swz(int wg, int nwg) {
    const int cpx = nwg >> 3;
    return (wg & 7) * cpx + (wg >> 3);
}

// ---------------------------------------------------------------------------
// 8-wave bf16 MFMA GEMM, PIPELINED: double-buffered LDS, STAGE(t+1) issued
// before COMPUTE(t), one barrier per K-step (vmcnt drain lands after MFMA).
// 128x128 tile, BK=64, 512 threads = 8 waves (2x4), wave = 64x32 output.
// SPLITK: grid.z=2, each block does K/2, writes f32 partial to Cp/Cp2.
// ---------------------------------------------------------------------------
template<int GELU, int OBF16, int SPLITK>
__global__ __launch_bounds__(512)
void gemm_mfma8(const ushort* __restrict__ A, const ushort* __restrict__ Bt,
                const float* __restrict__ bias, void* __restrict__ Cp,
                void* __restrict__ Cp2, int M, int N, int K)
{
    __shared__ ushort As[2][128 * 64];
    __shared__ ushort Bs[2][128 * 64];

    const int tid = threadIdx.x;
    const int w = tid >> 6, lane = tid & 63;
    const int lr = lane & 15, lg = lane >> 4;
    const int wr = w >> 2, wc = w & 3;

    const int gx = gridDim.x;
    const int wg = xcd_swz(blockIdx.y * gx + blockIdx.x, gx * gridDim.y);
    const int row0 = (wg / gx) * 128, col0 = (wg % gx) * 128;

    const int kLen = SPLITK ? (K >> 1) : K;
    const int kOff = SPLITK ? blockIdx.z * kLen : 0;

    const int srow = lane >> 3;
    const int schunk = (lane & 7) ^ srow;

    const ushort* aSrc = A  + (size_t)(row0 + w * 16 + srow) * K + kOff + schunk * 8;
    const ushort* bSrc = Bt + (size_t)(col0 + w * 16 + srow) * K + kOff + schunk * 8;

    f32x4 acc[4][2] = {};

    auto STAGE = [&](int buf, int k0) {
        ushort* aD = &As[buf][(w * 16) * 64];
        ushort* bD = &Bs[buf][(w * 16) * 64];
        gload16(aSrc + k0,                 aD);
        gload16(aSrc + (size_t)8 * K + k0, aD + 8 * 64);
        gload16(bSrc + k0,                 bD);
        gload16(bSrc + (size_t)8 * K + k0, bD + 8 * 64);
    };

    auto COMPUTE = [&](int buf) {
        const ushort* AsB = As[buf];
        const ushort* BsB = Bs[buf];
        #pragma unroll
        for (int kc = 0; kc < 2; ++kc) {
            bf16x8 af[4], bfr[2];
            #pragma unroll
            for (int mt = 0; mt < 4; ++mt)
                af[mt] = *(const bf16x8*)&AsB[(wr * 64 + mt * 16 + lr) * 64 +
                                             (((kc * 4 + lg) ^ (lr & 7)) * 8)];
            #pragma unroll
            for (int nt = 0; nt < 2; ++nt)
                bfr[nt] = *(const bf16x8*)&BsB[(wc * 32 + nt * 16 + lr) * 64 +
                                              (((kc * 4 + lg) ^ (lr & 7)) * 8)];
            __builtin_amdgcn_s_setprio(1);
            #pragma unroll
            for (int mt = 0; mt < 4; ++mt)
                #pragma unroll
                for (int nt = 0; nt < 2; ++nt)
                    acc[mt][nt] = __builtin_amdgcn_mfma_f32_16x16x32_bf16(
                        af[mt], bfr[nt], acc[mt][nt], 0, 0, 0);
            __builtin_amdgcn_s_setprio(0);
        }
    };

    const int nk = kLen >> 6;
    STAGE(0, 0);
    __syncthreads();
    for (int t = 0; t < nk; ++t) {
        if (t + 1 < nk) STAGE((t + 1) & 1, (t + 1) << 6);
        COMPUTE(t & 1);
        __syncthreads();
    }

    float* Pp = SPLITK ? (blockIdx.z ? (float*)Cp2 : (float*)Cp) : (float*)Cp;
    #pragma unroll
    for (int nt = 0; nt < 2; ++nt) {
        const int col = col0 + wc * 32 + nt * 16 + lr;
        const float bv = SPLITK ? 0.f : bias[col];
        #pragma unroll
        for (int mt = 0; mt < 4; ++mt) {
            #pragma unroll
            for (int i = 0; i < 4; ++i) {
                float o = acc[mt][nt][i] + bv;
                if (GELU) o = gelu_fast(o);
                const size_t idx = (size_t)(row0 + wr * 64 + mt * 16 + lg * 4 + i) * N + col;
                if (OBF16) ((ushort*)Cp)[idx] = f2bf(o);
                else       Pp[idx] = o;
            }
        }
    }
}

// ---------------------------------------------------------------------------
// 8-wave fused QKV GEMM, PIPELINED (+ XCD swizzle).
// A[8192,512] @ Wt^T + bias. Q cols (<512): *ATT_QSCALE bf16. K cols: bf16.
// V cols: transposed into vt.
// ---------------------------------------------------------------------------
__global__ __launch_bounds__(512)
void gemm_qkv8(const ushort* __restrict__ A, const ushort* __restrict__ Bt,
               const float* __restrict__ bias, ushort* __restrict__ qkv,
               ushort* __restrict__ vt)
{
    __shared__ ushort As[2][128 * 64];
    __shared__ ushort Bs[2][128 * 64];

    const int tid = threadIdx.x;
    const int w = tid >> 6, lane = tid & 63;
    const int lr = lane & 15, lg = lane >> 4;
    const int wr = w >> 2, wc = w & 3;

    const int gx = gridDim.x;   // 12
    const int wg = xcd_swz(blockIdx.y * gx + blockIdx.x, gx * gridDim.y);
    const int row0 = (wg / gx) * 128, col0 = (wg % gx) * 128;

    const int K = 512;

    const int srow = lane >> 3;
    const int schunk = (lane & 7) ^ srow;

    const ushort* aSrc = A  + (size_t)(row0 + w * 16 + srow) * K + schunk * 8;
    const ushort* bSrc = Bt + (size_t)(col0 + w * 16 + srow) * K + schunk * 8;

    f32x4 acc[4][2] = {};

    auto STAGE = [&](int buf, int k0) {
        ushort* aD = &As[buf][(w * 16) * 64];
        ushort* bD = &Bs[buf][(w * 16) * 64];
        gload16(aSrc + k0,                 aD);
        gload16(aSrc + (size_t)8 * K + k0, aD + 8 * 64);
        gload16(bSrc + k0,                 bD);
        gload16(bSrc + (size_t)8 * K + k0, bD + 8 * 64);
    };

    auto COMPUTE = [&](int buf) {
        const ushort* AsB = As[buf];
        const ushort* BsB = Bs[buf];
        #pragma unroll
        for (int kc = 0; kc < 2; ++kc) {
            bf16x8 af[4], bfr[2];
            #pragma unroll
            for (int mt = 0; mt < 4; ++mt)
                af[mt] = *(const bf16x8*)&AsB[(wr * 64 + mt * 16 + lr) * 64 +
                                             (((kc * 4 + lg) ^ (lr & 7)) * 8)];
            #pragma unroll
            for (int nt = 0; nt < 2; ++nt)
                bfr[nt] = *(const bf16x8*)&BsB[(wc * 32 + nt * 16 + lr) * 64 +
                                              (((kc * 4 + lg) ^ (lr & 7)) * 8)];
            __builtin_amdgcn_s_setprio(1);
            #pragma unroll
            for (int mt = 0; mt < 4; ++mt)
                #pragma unroll
                for (int nt = 0; nt < 2; ++nt)
                    acc[mt][nt] = __builtin_amdgcn_mfma_f32_16x16x32_bf16(
                        af[mt], bfr[nt], acc[mt][nt], 0, 0, 0);
            __builtin_amdgcn_s_setprio(0);
        }
    };

    STAGE(0, 0);
    __syncthreads();
    for (int t = 0; t < 8; ++t) {
        if (t + 1 < 8) STAGE((t + 1) & 1, (t + 1) << 6);
        COMPUTE(t & 1);
        __syncthreads();
    }

    #pragma unroll
    for (int nt = 0; nt < 2; ++nt) {
        const int col = col0 + wc * 32 + nt * 16 + lr;
        const float bv = bias[col];
        if (col < 1024) {
            const float sc = (col < 512) ? ATT_QSCALE : 1.0f;
            #pragma unroll
            for (int mt = 0; mt < 4; ++mt) {
                #pragma unroll
                for (int i = 0; i < 4; ++i) {
                    const float o = (acc[mt][nt][i] + bv) * sc;
                    qkv[(size_t)(row0 + wr * 64 + mt * 16 + lg * 4 + i) * QKVSTR + col] = f2bf(o);
                }
            }
        } else {
            const int hh = (col - 1024) >> 6, d = (col - 1024) & 63;
            #pragma unroll
            for (int mt = 0; mt < 4; ++mt) {
                const int rowb = row0 + wr * 64 + mt * 16 + lg * 4;
                const int bb = rowb >> 11, ss = rowb & (SEQ - 1);
                ushort4 o4;
                o4.x = f2bf(acc[mt][nt][0] + bv);
                o4.y = f2bf(acc[mt][nt][1] + bv);
                o4.z = f2bf(acc[mt][nt][2] + bv);
                o4.w = f2bf(acc[mt][nt][3] + bv);
                *(ushort4*)&vt[((size_t)(bb * NHEADS + hh) * HD + d) * SEQ + ss] = o4;
            }
        }
    }
}

// ---------------------------------------------------------------------------
// Flash attention: 8 waves = 4 q-subtiles x 2 KV-halves, XCD-chunked grid,
// within-wave QK/SM/PV interleave (R6).
// R7: LDS bank-conflict fix. R6 counter: SQ_LDS_BANK_CONFLICT = 2^22 exactly
// = 4 extra cyc x 2^20 ds_read_b128. Cause: fragment read row=l32 has byte
// addr l32*128 + chunk*16 -> bank set by chunk alone; chunk XOR used only
// l32&7, so lanes {x,x+8,x+16,x+24} shared a chunk -> 4-way conflict (1.58x,
// m136). Fix: second gload16 of each K/V 8-row group uses sslot^1 -> stored
// perm becomes (row&7)^((row>>3)&1); read chunk XORs the same parity bit.
// Alias quad splits into two pairs -> 2-way (free). GEMMs (lr=lane&15 rows,
// 2-way already) show 0 conflicts -- this brings attn to the same state.
// ---------------------------------------------------------------------------
#define KBLK 64
#define NKT (1024 / KBLK)

__global__ __launch_bounds__(512, 4)
void attn_mfma(const ushort* __restrict__ qkv, const ushort* __restrict__ vt,
               ushort* __restrict__ ctx)
{
    __shared__ __align__(16) ushort smem[2][2][2][64 * 64];   // [buf][half][K/V] 64 KiB

    const int tid = threadIdx.x;
    const int lane = tid & 63;
    const int l32 = lane & 31, hi = lane >> 5;
    const int w = tid >> 6;
    const int qsub = w & 3, half = w >> 2;

    // XCD swizzle: decode (qt,h,b) from the chunked flat id (qt fastest).
    const int flat = blockIdx.x + 16 * (blockIdx.y + 8 * blockIdx.z);
    const int wg = xcd_swz(flat, 512);
    const int qt = wg & 15, h = (wg >> 4) & 7, b = wg >> 7;

    const int q0 = qt * 128 + qsub * 32;
    const int kbase = half * 1024;

    const size_t seqbase = (size_t)b * SEQ;
    const ushort* Qp = qkv + (seqbase + q0 + l32) * QKVSTR + h * HD;
    const ushort* Kg = qkv + seqbase * QKVSTR + 512 + h * HD;
    const ushort* Vg = vt + (size_t)(b * NHEADS + h) * HD * SEQ;

    bf16x8 qf[4];
    #pragma unroll
    for (int c = 0; c < 4; ++c) qf[c] = *(const bf16x8*)&Qp[c * 16 + hi * 8];

    const int srow = lane >> 3;
    const int sslot  = (lane & 7) ^ srow;        // rows 0-7 of each 16-row group
    const int sslot2 = sslot ^ 1;                // rows 8-15: perm ^= 1 (conflict fix)
    const ushort* pK  = Kg + (size_t)(kbase + qsub * 16 + srow) * QKVSTR + sslot * 8;
    const ushort* pK2 = Kg + (size_t)(kbase + qsub * 16 + 8 + srow) * QKVSTR + sslot2 * 8;
    const ushort* pV  = Vg + (size_t)(qsub * 16 + srow) * SEQ + kbase + sslot * 8;
    const ushort* pV2 = Vg + (size_t)(qsub * 16 + 8 + srow) * SEQ + kbase + sslot2 * 8;

    // read-side permutation: perm(row) = (row&7) ^ ((row>>3)&1); same value
    // for row l32 and row 32+l32 (bit4 doesn't touch parity).
    const int pswz = (l32 & 7) ^ ((l32 >> 3) & 1);

    f32x16 o0 = {}, o1 = {};
    float l = 0.f;

    auto STAGE = [&](int buf) {
        ushort* dK = &smem[buf][half][0][(qsub * 16) * 64];
        ushort* dV = &smem[buf][half][1][(qsub * 16) * 64];
        gload16(pK,  dK);
        gload16(pK2, dK + 8 * 64);
        gload16(pV,  dV);
        gload16(pV2, dV + 8 * 64);
        pK  += (size_t)KBLK * QKVSTR;
        pK2 += (size_t)KBLK * QKVSTR;
        pV  += KBLK;
        pV2 += KBLK;
    };

    auto COMPUTE = [&](int buf) {
        const ushort* KsH = &smem[buf][half][0][0];
        const ushort* VsH = &smem[buf][half][1][0];

        f32x16 s0 = {}, s1 = {};

        // QK for s0 (pure MFMA cluster, nothing to interleave yet)
        __builtin_amdgcn_s_setprio(1);
        #pragma unroll
        for (int c = 0; c < 4; ++c) {
            const bf16x8 kf0 = *(const bf16x8*)&KsH[l32 * 64 + (((2 * c + hi) ^ pswz) * 8)];
            s0 = __builtin_amdgcn_mfma_f32_32x32x16_bf16(kf0, qf[c], s0, 0, 0, 0);
        }
        __builtin_amdgcn_s_setprio(0);

        // QK for s1 — independent of SM(s0) below; no fences so the
        // scheduler interleaves these MFMAs with s0's exp2/cvt chain.
        #pragma unroll
        for (int c = 0; c < 4; ++c) {
            const bf16x8 kf1 = *(const bf16x8*)&KsH[(32 + l32) * 64 + (((2 * c + hi) ^ pswz) * 8)];
            s1 = __builtin_amdgcn_mfma_f32_32x32x16_bf16(kf1, qf[c], s1, 0, 0, 0);
        }

        float ts = 0.f;
        unsigned wp[16];
        union { unsigned u[4]; bf16x8 v; } pb[4];

        // SM(s0) -> pb[0], pb[1]
        #pragma unroll
        for (int r = 0; r < 16; ++r) { s0[r] = exp2_hw(s0[r]); ts += s0[r]; }
        #pragma unroll
        for (int j = 0; j < 8; ++j) wp[j] = cvt_pk_bf16(s0[2 * j], s0[2 * j + 1]);
        plswap(wp[0], wp[2]);  plswap(wp[1], wp[3]);
        plswap(wp[4], wp[6]);  plswap(wp[5], wp[7]);
        pb[0].u[0] = wp[0]; pb[0].u[1] = wp[1]; pb[0].u[2] = wp[2]; pb[0].u[3] = wp[3];
        pb[1].u[0] = wp[4]; pb[1].u[1] = wp[5]; pb[1].u[2] = wp[6]; pb[1].u[3] = wp[7];

        // PV kg=0,1 (s0-derived) — independent of SM(s1) below.
        #pragma unroll
        for (int kg = 0; kg < 2; ++kg) {
            const bf16x8 vf0 = *(const bf16x8*)&VsH[l32 * 64 + (((2 * kg + hi) ^ pswz) * 8)];
            o0 = __builtin_amdgcn_mfma_f32_32x32x16_bf16(vf0, pb[kg].v, o0, 0, 0, 0);
            const bf16x8 vf1 = *(const bf16x8*)&VsH[(32 + l32) * 64 + (((2 * kg + hi) ^ pswz) * 8)];
            o1 = __builtin_amdgcn_mfma_f32_32x32x16_bf16(vf1, pb[kg].v, o1, 0, 0, 0);
        }

        // SM(s1) -> pb[2], pb[3] (interleaves with the PV MFMAs above)
        #pragma unroll
        for (int r = 0; r < 16; ++r) { s1[r] = exp2_hw(s1[r]); ts += s1[r]; }
        #pragma unroll
        for (int j = 0; j < 8; ++j) wp[8 + j] = cvt_pk_bf16(s1[2 * j], s1[2 * j + 1]);
        plswap(wp[8], wp[10]);  plswap(wp[9], wp[11]);
        plswap(wp[12], wp[14]); plswap(wp[13], wp[15]);
        pb[2].u[0] = wp[8];  pb[2].u[1] = wp[9];  pb[2].u[2] = wp[10]; pb[2].u[3] = wp[11];
        pb[3].u[0] = wp[12]; pb[3].u[1] = wp[13]; pb[3].u[2] = wp[14]; pb[3].u[3] = wp[15];

        // PV kg=2,3
        #pragma unroll
        for (int kg = 2; kg < 4; ++kg) {
            const bf16x8 vf0 = *(const bf16x8*)&VsH[l32 * 64 + (((2 * kg + hi) ^ pswz) * 8)];
            o0 = __builtin_amdgcn_mfma_f32_32x32x16_bf16(vf0, pb[kg].v, o0, 0, 0, 0);
            const bf16x8 vf1 = *(const bf16x8*)&VsH[(32 + l32) * 64 + (((2 * kg + hi) ^ pswz) * 8)];
            o1 = __builtin_amdgcn_mfma_f32_32x32x16_bf16(vf1, pb[kg].v, o1, 0, 0, 0);
        }

        l += ts;
    };

    STAGE(0);
    __syncthreads();
    for (int tt = 0; tt < NKT; tt += 2) {
        if (tt + 1 < NKT) STAGE(1);
        COMPUTE(0);
        __syncthreads();
        if (tt + 2 < NKT) STAGE(0);
        COMPUTE(1);
        __syncthreads();
    }

    { float a_ = l, b_ = l; plswapf(a_, b_); l = a_ + b_; }

    // ---- merge the two KV-halves per q-subtile (plain sums) ----
    float* so = (float*)smem;                             // [4][64][33]
    float* sl = (float*)((char*)smem + 4 * 64 * 33 * 4);  // [4][64]
    if (half) {
        float* row = so + (qsub * 64 + lane) * 33;
        #pragma unroll
        for (int r = 0; r < 16; ++r) row[r] = o0[r];
        #pragma unroll
        for (int r = 0; r < 16; ++r) row[16 + r] = o1[r];
        sl[qsub * 64 + lane] = l;
    }
    __syncthreads();
    if (!half) {
        const float lb = sl[qsub * 64 + lane];
        const float* row = so + (qsub * 64 + lane) * 33;
        const float inv = 1.f / (l + lb);

        ushort* dst = ctx + (seqbase + q0 + l32) * D + h * HD;
        #pragma unroll
        for (int g = 0; g < 4; ++g) {
            ushort4 t0, t1;
            t0.x = f2bf((o0[g * 4 + 0] + row[g * 4 + 0]) * inv);
            t0.y = f2bf((o0[g * 4 + 1] + row[g * 4 + 1]) * inv);
            t0.z = f2bf((o0[g * 4 + 2] + row[g * 4 + 2]) * inv);
            t0.w = f2bf((o0[g * 4 + 3] + row[g * 4 + 3]) * inv);
            t1.x = f2bf((o1[g * 4 + 0] + row[16 + g * 4 + 0]) * inv);
            t1.y = f2bf((o1[g * 4 + 1] + row[16 + g * 4 + 1]) * inv);
            t1.z = f2bf((o1[g * 4 + 2] + row[16 + g * 4 + 2]) * inv);
            t1.w = f2bf((o1[g * 4 + 3] + row[16 + g * 4 + 3]) * inv);
            *(ushort4*)&dst[g * 8 + hi * 4]      = t0;
            *(ushort4*)&dst[32 + g * 8 + hi * 4] = t1;
        }
    }
}

// ---------------------------------------------------------------------------
// out = LayerNorm(res + b0 + b1 + bias) * g + beta.
// ---------------------------------------------------------------------------
template<int RESBF, int OUTBF>
__global__ __launch_bounds__(256)
void add_ln3(const void* __restrict__ res, const float* __restrict__ b0,
             const float* __restrict__ b1, const float* __restrict__ bias,
             const float* __restrict__ g, const float* __restrict__ beta,
             float* __restrict__ outf, ushort* __restrict__ outb)
{
    const int wave = threadIdx.x >> 6, lane = threadIdx.x & 63;
    const size_t row = (size_t)blockIdx.x * 4 + wave;

    float xr[8];
    if (RESBF) {
        const ushort* pr = (const ushort*)res + row * D + lane * 8;
        const ushort4 r0 = *(const ushort4*)pr;
        const ushort4 r1 = *(const ushort4*)(pr + 4);
        xr[0] = bf2f(r0.x); xr[1] = bf2f(r0.y); xr[2] = bf2f(r0.z); xr[3] = bf2f(r0.w);
        xr[4] = bf2f(r1.x); xr[5] = bf2f(r1.y); xr[6] = bf2f(r1.z); xr[7] = bf2f(r1.w);
    } else {
        const float* pr = (const float*)res + row * D + lane * 8;
        const float4 r0 = *(const float4*)pr;
        const float4 r1 = *(const float4*)(pr + 4);
        xr[0] = r0.x; xr[1] = r0.y; xr[2] = r0.z; xr[3] = r0.w;
        xr[4] = r1.x; xr[5] = r1.y; xr[6] = r1.z; xr[7] = r1.w;
    }

    const float* p0 = &b0[row * D + lane * 8];
    const float* p1 = &b1[row * D + lane * 8];
    const float4 c0 = *(const float4*)p0;
    const float4 c1 = *(const float4*)(p0 + 4);
    const float4 d0 = *(const float4*)p1;
    const float4 d1 = *(const float4*)(p1 + 4);
    const float4 bb0 = *(const float4*)&bias[lane * 8];
    const float4 bb1 = *(const float4*)&bias[lane * 8 + 4];

    float x[8];
    x[0] = xr[0] + c0.x + d0.x + bb0.x; x[1] = xr[1] + c0.y + d0.y + bb0.y;
    x[2] = xr[2] + c0.z + d0.z + bb0.z; x[3] = xr[3] + c0.w + d0.w + bb0.w;
    x[4] = xr[4] + c1.x + d1.x + bb1.x; x[5] = xr[5] + c1.y + d1.y + bb1.y;
    x[6] = xr[6] + c1.z + d1.z + bb1.z; x[7] = xr[7] + c1.w + d1.w + bb1.w;

    float sum = 0.f;
    #pragma unroll
    for (int i = 0; i < 8; ++i) sum += x[i];
    #pragma unroll
    for (int off = 32; off >= 1; off >>= 1) sum += __shfl_xor(sum, off);
    const float mu = sum * (1.0f / D);

    float vsum = 0.f;
    #pragma unroll
    for (int i = 0; i < 8; ++i) { const float dxe = x[i] - mu; vsum += dxe * dxe; }
    #pragma unroll
    for (int off = 32; off >= 1; off >>= 1) vsum += __shfl_xor(vsum, off);
    const float rs = rsqrtf(vsum * (1.0f / D) + 1e-5f);

    const float4 g0  = *(const float4*)&g[lane * 8];
    const float4 g1v = *(const float4*)&g[lane * 8 + 4];
    const float4 be0 = *(const float4*)&beta[lane * 8];
    const float4 be1 = *(const float4*)&beta[lane * 8 + 4];

    float o[8];
    o[0] = (x[0] - mu) * rs * g0.x  + be0.x;
    o[1] = (x[1] - mu) * rs * g0.y  + be0.y;
    o[2] = (x[2] - mu) * rs * g0.z  + be0.z;
    o[3] = (x[3] - mu) * rs * g0.w  + be0.w;
    o[4] = (x[4] - mu) * rs * g1v.x + be1.x;
    o[5] = (x[5] - mu) * rs * g1v.y + be1.y;
    o[6] = (x[6] - mu) * rs * g1v.z + be1.z;
    o[7] = (x[7] - mu) * rs * g1v.w + be1.w;

    if (OUTBF) {
        ushort4 lo, hi;
        lo.x = f2bf(o[0]); lo.y = f2bf(o[1]); lo.z = f2bf(o[2]); lo.w = f2bf(o[3]);
        hi.x = f2bf(o[4]); hi.y = f2bf(o[5]); hi.z = f2bf(o[6]); hi.w = f2bf(o[7]);
        ushort* pq = &outb[row * D + lane * 8];
        *(ushort4*)pq       = lo;
        *(ushort4*)(pq + 4) = hi;
    } else {
        float* po = &outf[row * D + lane * 8];
        *(float4*)po       = *(float4*)&o[0];
        *(float4*)(po + 4) = *(float4*)&o[4];
    }
}

// ---------------------------------------------------------------------------
// Fused prologue: x cast (blocks 0..2047), weight transposes (2048..5119),
// bias concat (5120..5125).
// ---------------------------------------------------------------------------
__global__ __launch_bounds__(256)
void prep(const float* __restrict__ x, ushort* __restrict__ x_bf,
          const float* __restrict__ wq, const float* __restrict__ wk,
          const float* __restrict__ wv, const float* __restrict__ wo,
          const float* __restrict__ w_up, const float* __restrict__ w_down,
          ushort* __restrict__ Wt_qkv, ushort* __restrict__ Wt_o,
          ushort* __restrict__ Wt_up, ushort* __restrict__ Wt_down,
          const float* __restrict__ bq, const float* __restrict__ bk,
          const float* __restrict__ bv, float* __restrict__ b_qkv)
{
    const int bid = blockIdx.x;
    const int tid = threadIdx.x;

    if (bid < 2048) {
        const int i = bid * 256 + tid;
        const float4 a = *(const float4*)&x[(size_t)i * 8];
        const float4 b = *(const float4*)&x[(size_t)i * 8 + 4];
        ushort4 lo, hi;
        lo.x = f2bf(a.x); lo.y = f2bf(a.y); lo.z = f2bf(a.z); lo.w = f2bf(a.w);
        hi.x = f2bf(b.x); hi.y = f2bf(b.y); hi.z = f2bf(b.z); hi.w = f2bf(b.w);
        *(ushort4*)&x_bf[(size_t)i * 8]     = lo;
        *(ushort4*)&x_bf[(size_t)i * 8 + 4] = hi;
        return;
    }

    if (bid < 5120) {
        __shared__ float t[32][33];
        const int j = bid - 2048;
        const float* W; ushort* Wt; int N, stride, tI;
        if (j < 256)       { W = wq;     Wt = Wt_qkv;              N = 512;  stride = 512;  tI = j; }
        else if (j < 512)  { W = wk;     Wt = Wt_qkv + 512 * 512;  N = 512;  stride = 512;  tI = j - 256; }
        else if (j < 768)  { W = wv;     Wt = Wt_qkv + 1024 * 512; N = 512;  stride = 512;  tI = j - 512; }
        else if (j < 1024) { W = wo;     Wt = Wt_o;                N = 512;  stride = 512;  tI = j - 768; }
        else if (j < 2048) { W = w_up;   Wt = Wt_up;               N = 2048; stride = 512;  tI = j - 1024; }
        else               { W = w_down; Wt = Wt_down;             N = 512;  stride = 2048; tI = j - 2048; }
        const int ntn = N >> 5;
        const int n0 = (tI % ntn) * 32, k0 = (tI / ntn) * 32;
        const int r = tid >> 5, c = tid & 31;
        #pragma unroll
        for (int i = 0; i < 4; ++i)
            t[r + i * 8][c] = W[(size_t)(k0 + r + i * 8) * N + n0 + c];
        __syncthreads();
        #pragma unroll
        for (int i = 0; i < 4; ++i)
            Wt[(size_t)(n0 + r + i * 8) * stride + k0 + c] = f2bf(t[c][r + i * 8]);
        return;
    }

    const int i = (bid - 5120) * 256 + tid;
    if (i < 1536)
        b_qkv[i] = (i < 512) ? bq[i] : (i < 1024 ? bk[i - 512] : bv[i - 1024]);
}

// ---------------------------------------------------------------------------
extern "C" void kernel_launch(void* const* d_in, const int* in_sizes, int n_in,
                              void* d_out, int out_size, void* d_ws, size_t ws_size,
                              hipStream_t stream)
{
    const float* x      = (const float*)d_in[0];
    const float* wq     = (const float*)d_in[1];
    const float* bq     = (const float*)d_in[2];
    const float* wk     = (const float*)d_in[3];
    const float* bk     = (const float*)d_in[4];
    const float* wv     = (const float*)d_in[5];
    const float* bv     = (const float*)d_in[6];
    const float* wo     = (const float*)d_in[7];
    const float* bo     = (const float*)d_in[8];
    const float* w_up   = (const float*)d_in[9];
    const float* b_up   = (const float*)d_in[10];
    const float* w_down = (const float*)d_in[11];
    const float* b_down = (const float*)d_in[12];
    const float* g1     = (const float*)d_in[13];
    const float* beta1  = (const float*)d_in[14];
    const float* g2     = (const float*)d_in[15];
    const float* beta2  = (const float*)d_in[16];
    float* out = (float*)d_out;

    // workspace layout (MiB offsets); all lifetimes verified, peak 96 MiB.
    char* wsb = (char*)d_ws;
    #define WS(ofs_mb) (wsb + ((size_t)(ofs_mb) << 20))
    ushort* Wt_qkv  = (ushort*)WS(0);    // [0,2)   live->QKV gemm
    ushort* Wt_o    = (ushort*)WS(2);    // [2,3)   live->O gemm
    ushort* Wt_up   = (ushort*)WS(3);    // [3,5)   live->up gemm
    ushort* Wt_down = (ushort*)WS(5);    // [5,7)   live->down gemm
    float*  b_qkv   = (float*) WS(7);    // [7,8)
    ushort* x_bf    = (ushort*)WS(8);    // [8,16)  live->QKV gemm
    ushort* qkv_bf  = (ushort*)WS(16);   // [16,40) live->attn
    ushort* vt_bf   = (ushort*)WS(40);   // [40,48) live->attn
    ushort* ctx_bf  = (ushort*)WS(48);   // [48,56) live->O gemm
    float*  yp0     = (float*) WS(8);    // [8,24)  O partial 0 (x_bf/qkv dead)
    float*  yp1     = (float*) WS(24);   // [24,40) O partial 1
    ushort* x1_bf   = (ushort*)WS(40);   // [40,48) ln1 out (vt dead); residual for ln2
    ushort* h_bf    = (ushort*)WS(8);    // [8,40)  up out (yp dead)
    float*  y2p0    = (float*) WS(64);   // [64,80) down partial 0
    float*  y2p1    = (float*) WS(80);   // [80,96) down partial 1
    #undef WS

    const dim3 blk(256), blk8(512);

    prep<<<dim3(5126), blk, 0, stream>>>(x, x_bf, wq, wk, wv, wo, w_up, w_down,
                                         Wt_qkv, Wt_o, Wt_up, Wt_down,
                                         bq, bk, bv, b_qkv);

    gemm_qkv8<<<dim3(12, 64), blk8, 0, stream>>>(x_bf, Wt_qkv, b_qkv, qkv_bf, vt_bf);

    attn_mfma<<<dim3(SEQ / 128, NHEADS, BATCH), blk8, 0, stream>>>(qkv_bf, vt_bf, ctx_bf);

    // O-proj split-K x2 -> f32 partials; bias folded into ln1
    gemm_mfma8<0, 0, 1><<<dim3(4, 64, 2), blk8, 0, stream>>>(ctx_bf, Wt_o, nullptr, yp0, yp1, MROWS, 512, 512);
    add_ln3<0, 1><<<dim3(MROWS / 4), blk, 0, stream>>>(x, yp0, yp1, bo, g1, beta1, nullptr, x1_bf);

    // FFN up + GELU -> bf16 h
    gemm_mfma8<1, 1, 0><<<dim3(16, 64), blk8, 0, stream>>>(x1_bf, Wt_up, b_up, h_bf, nullptr, MROWS, 2048, 512);
    // down split-K x2 -> f32 partials; bias folded into ln2
    gemm_mfma8<0, 0, 1><<<dim3(4, 64, 2), blk8, 0, stream>>>(h_bf, Wt_down, nullptr, y2p0, y2p1, MROWS, 512, 2048);
    add_ln3<1, 0><<<dim3(MROWS / 4), blk, 0, stream>>>(x1_bf, y2p0, y2p1, b_down, g2, beta2, out, nullptr);
}

// Round 8
// 144.112 us; speedup vs baseline: 1.0307x; 1.0307x over previous
//
#include <hip/hip_runtime.h>
#include <math.h>

#define D 512
#define NHEADS 8
#define HD 64
#define SEQ 2048
#define BATCH 4
#define MROWS (BATCH*SEQ)
#define QKVSTR 1536
// (1/sqrt(512)) * log2(e): Q pre-scale so softmax runs in exp2 domain
#define ATT_QSCALE 0.06376228841159383f

typedef short bf16x8 __attribute__((ext_vector_type(8)));
typedef float f32x4 __attribute__((ext_vector_type(4)));
typedef float f32x16 __attribute__((ext_vector_type(16)));

__device__ __forceinline__ ushort f2bf(float f) {
    union { float f; unsigned u; } v; v.f = f;
    unsigned r = (v.u + 0x7fffu + ((v.u >> 16) & 1u)) >> 16;
    return (ushort)r;
}
__device__ __forceinline__ float bf2f(ushort u) {
    union { unsigned u; float f; } v; v.u = ((unsigned)u) << 16; return v.f;
}

__device__ __forceinline__ unsigned cvt_pk_bf16(float lo, float hi_) {
    unsigned r;
    asm("v_cvt_pk_bf16_f32 %0, %1, %2" : "=v"(r) : "v"(lo), "v"(hi_));
    return r;
}

// 2^x via the transcendental unit (input already in log2 domain)
__device__ __forceinline__ float exp2_hw(float x) {
    float r;
    asm("v_exp_f32 %0, %1" : "=v"(r) : "v"(x));
    return r;
}
__device__ __forceinline__ float rcp_hw(float x) {
    float r;
    asm("v_rcp_f32 %0, %1" : "=v"(r) : "v"(x));
    return r;
}

// Fast exact-GELU: erf via Abramowitz-Stegun 7.1.26 (|err| <= ~2e-5 with HW
// rcp) on the transcendental unit. Replaced libm erff in R6: up-GEMM left the
// top-5 (~3 us), absmax unchanged.
__device__ __forceinline__ float gelu_fast(float x) {
    const float z = fabsf(x) * 0.70710678118654752f;
    const float t = rcp_hw(fmaf(0.3275911f, z, 1.0f));
    float p = fmaf(1.061405429f, t, -1.453152027f);
    p = fmaf(p, t, 1.421413741f);
    p = fmaf(p, t, -0.284496736f);
    p = fmaf(p, t, 0.254829592f);
    const float e = exp2_hw(-z * z * 1.4426950408889634f);
    const float erfz = 1.0f - p * t * e;        // erf(|x|/sqrt(2))
    const float s = copysignf(erfz, x);
    return 0.5f * x * (1.0f + s);
}

// v_permlane32_swap_b32: swaps the lower 32 lanes of a with upper 32 lanes of b.
__device__ __forceinline__ void plswap(unsigned &a, unsigned &b) {
    asm("v_permlane32_swap_b32 %0, %1" : "+v"(a), "+v"(b));
}
__device__ __forceinline__ void plswapf(float &a, float &b) {
    union { float f; unsigned u; } ua, ub;
    ua.f = a; ub.f = b;
    asm("v_permlane32_swap_b32 %0, %1" : "+v"(ua.u), "+v"(ub.u));
    a = ua.f; b = ub.f;
}

// global -> LDS direct copy, 16B per lane. LDS dest = wave-uniform base + lane*16.
__device__ __forceinline__ void gload16(const void* g, void* lds) {
    __builtin_amdgcn_global_load_lds(
        (const __attribute__((address_space(1))) unsigned int*)(uintptr_t)g,
        (__attribute__((address_space(3))) unsigned int*)(uintptr_t)lds,
        16, 0, 0);
}

// XCD-chunked bijective block swizzle (T1). R4 verified on up-GEMM: FETCH
// 35.5 -> 20.7 MB (8-XCD compulsory floor), dur 53.5 -> 47 us. R5 verified
// on attn: FETCH 69.7 -> 12.3 MB. Requires nwg % 8 == 0.
__device__ __forceinline__ int xcd_swz(int wg, int nwg) {
    const int cpx = nwg >> 3;
    return (wg & 7) * cpx + (wg >> 3);
}

// ---------------------------------------------------------------------------
// 8-wave bf16 MFMA GEMM, PIPELINED: double-buffered LDS, STAGE(t+1) issued
// before COMPUTE(t), one barrier per K-step. 128x128 tile, BK=64,
// 512 threads = 8 waves (2x4), wave = 64x32 output. Used for the up-proj.
// ---------------------------------------------------------------------------
template<int GELU, int OBF16>
__global__ __launch_bounds__(512)
void gemm_mfma8(const ushort* __restrict__ A, const ushort* __restrict__ Bt,
                const float* __restrict__ bias, void* __restrict__ Cp,
                int M, int N, int K)
{
    __shared__ ushort As[2][128 * 64];
    __shared__ ushort Bs[2][128 * 64];

    const int tid = threadIdx.x;
    const int w = tid >> 6, lane = tid & 63;
    const int lr = lane & 15, lg = lane >> 4;
    const int wr = w >> 2, wc = w & 3;

    const int gx = gridDim.x;
    const int wg = xcd_swz(blockIdx.y * gx + blockIdx.x, gx * gridDim.y);
    const int row0 = (wg / gx) * 128, col0 = (wg % gx) * 128;

    const int srow = lane >> 3;
    const int schunk = (lane & 7) ^ srow;

    const ushort* aSrc = A  + (size_t)(row0 + w * 16 + srow) * K + schunk * 8;
    const ushort* bSrc = Bt + (size_t)(col0 + w * 16 + srow) * K + schunk * 8;

    f32x4 acc[4][2] = {};

    auto STAGE = [&](int buf, int k0) {
        ushort* aD = &As[buf][(w * 16) * 64];
        ushort* bD = &Bs[buf][(w * 16) * 64];
        gload16(aSrc + k0,                 aD);
        gload16(aSrc + (size_t)8 * K + k0, aD + 8 * 64);
        gload16(bSrc + k0,                 bD);
        gload16(bSrc + (size_t)8 * K + k0, bD + 8 * 64);
    };

    auto COMPUTE = [&](int buf) {
        const ushort* AsB = As[buf];
        const ushort* BsB = Bs[buf];
        #pragma unroll
        for (int kc = 0; kc < 2; ++kc) {
            bf16x8 af[4], bfr[2];
            #pragma unroll
            for (int mt = 0; mt < 4; ++mt)
                af[mt] = *(const bf16x8*)&AsB[(wr * 64 + mt * 16 + lr) * 64 +
                                             (((kc * 4 + lg) ^ (lr & 7)) * 8)];
            #pragma unroll
            for (int nt = 0; nt < 2; ++nt)
                bfr[nt] = *(const bf16x8*)&BsB[(wc * 32 + nt * 16 + lr) * 64 +
                                              (((kc * 4 + lg) ^ (lr & 7)) * 8)];
            __builtin_amdgcn_s_setprio(1);
            #pragma unroll
            for (int mt = 0; mt < 4; ++mt)
                #pragma unroll
                for (int nt = 0; nt < 2; ++nt)
                    acc[mt][nt] = __builtin_amdgcn_mfma_f32_16x16x32_bf16(
                        af[mt], bfr[nt], acc[mt][nt], 0, 0, 0);
            __builtin_amdgcn_s_setprio(0);
        }
    };

    const int nk = K >> 6;
    STAGE(0, 0);
    __syncthreads();
    for (int t = 0; t < nk; ++t) {
        if (t + 1 < nk) STAGE((t + 1) & 1, (t + 1) << 6);
        COMPUTE(t & 1);
        __syncthreads();
    }

    #pragma unroll
    for (int nt = 0; nt < 2; ++nt) {
        const int col = col0 + wc * 32 + nt * 16 + lr;
        const float bv = bias[col];
        #pragma unroll
        for (int mt = 0; mt < 4; ++mt) {
            #pragma unroll
            for (int i = 0; i < 4; ++i) {
                float o = acc[mt][nt][i] + bv;
                if (GELU) o = gelu_fast(o);
                const size_t idx = (size_t)(row0 + wr * 64 + mt * 16 + lg * 4 + i) * N + col;
                if (OBF16) ((ushort*)Cp)[idx] = f2bf(o);
                else       ((float*)Cp)[idx] = o;
            }
        }
    }
}

// ---------------------------------------------------------------------------
// R8: 128x64-tile GEMM, NO split-K, f32 out — replaces the split-K O/down
// GEMMs. Rationale: split-K x2 existed only to reach 512 blocks (2/CU); the
// same count comes from splitting N=512 into 8 col-tiles of 64. Each block
// then owns the full K-sum -> the 32 MB f32 partial write + 32 MB LN re-read
// per GEMM disappears (-64 MB HBM total), numerically identical (f32 y kept).
// 8 waves = 4 M-quadrants x 2 N-halves, wave = 32x32 out, acc[2][2].
// Mapping is a strict subset of the R3-refchecked BN=128 layout.
// LDS: A 2x16KB + B 2x8KB = 48 KiB.
// ---------------------------------------------------------------------------
__global__ __launch_bounds__(512)
void gemm_n64(const ushort* __restrict__ A, const ushort* __restrict__ Bt,
              float* __restrict__ Y, int N, int K)
{
    __shared__ ushort As[2][128 * 64];
    __shared__ ushort Bs[2][64 * 64];

    const int tid = threadIdx.x;
    const int w = tid >> 6, lane = tid & 63;
    const int lr = lane & 15, lg = lane >> 4;
    const int wr = w >> 1, wc = w & 1;

    const int gx = gridDim.x;   // 8 col-tiles of 64
    const int wg = xcd_swz(blockIdx.y * gx + blockIdx.x, gx * gridDim.y);
    const int row0 = (wg / gx) * 128, col0 = (wg % gx) * 64;

    const int srow = lane >> 3;
    const int schunk = (lane & 7) ^ srow;

    const ushort* aSrc = A  + (size_t)(row0 + w * 16 + srow) * K + schunk * 8;
    const ushort* bSrc = Bt + (size_t)(col0 + w * 8 + srow) * K + schunk * 8;

    f32x4 acc[2][2] = {};

    auto STAGE = [&](int buf, int k0) {
        ushort* aD = &As[buf][(w * 16) * 64];
        gload16(aSrc + k0,                 aD);
        gload16(aSrc + (size_t)8 * K + k0, aD + 8 * 64);
        gload16(bSrc + k0, &Bs[buf][(w * 8) * 64]);
    };

    auto COMPUTE = [&](int buf) {
        const ushort* AsB = As[buf];
        const ushort* BsB = Bs[buf];
        #pragma unroll
        for (int kc = 0; kc < 2; ++kc) {
            bf16x8 af[2], bfr[2];
            #pragma unroll
            for (int mt = 0; mt < 2; ++mt)
                af[mt] = *(const bf16x8*)&AsB[(wr * 32 + mt * 16 + lr) * 64 +
                                             (((kc * 4 + lg) ^ (lr & 7)) * 8)];
            #pragma unroll
            for (int nt = 0; nt < 2; ++nt)
                bfr[nt] = *(const bf16x8*)&BsB[(wc * 32 + nt * 16 + lr) * 64 +
                                              (((kc * 4 + lg) ^ (lr & 7)) * 8)];
            __builtin_amdgcn_s_setprio(1);
            #pragma unroll
            for (int mt = 0; mt < 2; ++mt)
                #pragma unroll
                for (int nt = 0; nt < 2; ++nt)
                    acc[mt][nt] = __builtin_amdgcn_mfma_f32_16x16x32_bf16(
                        af[mt], bfr[nt], acc[mt][nt], 0, 0, 0);
            __builtin_amdgcn_s_setprio(0);
        }
    };

    const int nk = K >> 6;
    STAGE(0, 0);
    __syncthreads();
    for (int t = 0; t < nk; ++t) {
        if (t + 1 < nk) STAGE((t + 1) & 1, (t + 1) << 6);
        COMPUTE(t & 1);
        __syncthreads();
    }

    #pragma unroll
    for (int nt = 0; nt < 2; ++nt) {
        const int col = col0 + wc * 32 + nt * 16 + lr;
        #pragma unroll
        for (int mt = 0; mt < 2; ++mt) {
            #pragma unroll
            for (int i = 0; i < 4; ++i) {
                const size_t idx = (size_t)(row0 + wr * 32 + mt * 16 + lg * 4 + i) * N + col;
                Y[idx] = acc[mt][nt][i];
            }
        }
    }
}

// ---------------------------------------------------------------------------
// 8-wave fused QKV GEMM, PIPELINED (+ XCD swizzle).
// A[8192,512] @ Wt^T + bias. Q cols (<512): *ATT_QSCALE bf16. K cols: bf16.
// V cols: transposed into vt.
// ---------------------------------------------------------------------------
__global__ __launch_bounds__(512)
void gemm_qkv8(const ushort* __restrict__ A, const ushort* __restrict__ Bt,
               const float* __restrict__ bias, ushort* __restrict__ qkv,
               ushort* __restrict__ vt)
{
    __shared__ ushort As[2][128 * 64];
    __shared__ ushort Bs[2][128 * 64];

    const int tid = threadIdx.x;
    const int w = tid >> 6, lane = tid & 63;
    const int lr = lane & 15, lg = lane >> 4;
    const int wr = w >> 2, wc = w & 3;

    const int gx = gridDim.x;   // 12
    const int wg = xcd_swz(blockIdx.y * gx + blockIdx.x, gx * gridDim.y);
    const int row0 = (wg / gx) * 128, col0 = (wg % gx) * 128;

    const int K = 512;

    const int srow = lane >> 3;
    const int schunk = (lane & 7) ^ srow;

    const ushort* aSrc = A  + (size_t)(row0 + w * 16 + srow) * K + schunk * 8;
    const ushort* bSrc = Bt + (size_t)(col0 + w * 16 + srow) * K + schunk * 8;

    f32x4 acc[4][2] = {};

    auto STAGE = [&](int buf, int k0) {
        ushort* aD = &As[buf][(w * 16) * 64];
        ushort* bD = &Bs[buf][(w * 16) * 64];
        gload16(aSrc + k0,                 aD);
        gload16(aSrc + (size_t)8 * K + k0, aD + 8 * 64);
        gload16(bSrc + k0,                 bD);
        gload16(bSrc + (size_t)8 * K + k0, bD + 8 * 64);
    };

    auto COMPUTE = [&](int buf) {
        const ushort* AsB = As[buf];
        const ushort* BsB = Bs[buf];
        #pragma unroll
        for (int kc = 0; kc < 2; ++kc) {
            bf16x8 af[4], bfr[2];
            #pragma unroll
            for (int mt = 0; mt < 4; ++mt)
                af[mt] = *(const bf16x8*)&AsB[(wr * 64 + mt * 16 + lr) * 64 +
                                             (((kc * 4 + lg) ^ (lr & 7)) * 8)];
            #pragma unroll
            for (int nt = 0; nt < 2; ++nt)
                bfr[nt] = *(const bf16x8*)&BsB[(wc * 32 + nt * 16 + lr) * 64 +
                                              (((kc * 4 + lg) ^ (lr & 7)) * 8)];
            __builtin_amdgcn_s_setprio(1);
            #pragma unroll
            for (int mt = 0; mt < 4; ++mt)
                #pragma unroll
                for (int nt = 0; nt < 2; ++nt)
                    acc[mt][nt] = __builtin_amdgcn_mfma_f32_16x16x32_bf16(
                        af[mt], bfr[nt], acc[mt][nt], 0, 0, 0);
            __builtin_amdgcn_s_setprio(0);
        }
    };

    STAGE(0, 0);
    __syncthreads();
    for (int t = 0; t < 8; ++t) {
        if (t + 1 < 8) STAGE((t + 1) & 1, (t + 1) << 6);
        COMPUTE(t & 1);
        __syncthreads();
    }

    #pragma unroll
    for (int nt = 0; nt < 2; ++nt) {
        const int col = col0 + wc * 32 + nt * 16 + lr;
        const float bv = bias[col];
        if (col < 1024) {
            const float sc = (col < 512) ? ATT_QSCALE : 1.0f;
            #pragma unroll
            for (int mt = 0; mt < 4; ++mt) {
                #pragma unroll
                for (int i = 0; i < 4; ++i) {
                    const float o = (acc[mt][nt][i] + bv) * sc;
                    qkv[(size_t)(row0 + wr * 64 + mt * 16 + lg * 4 + i) * QKVSTR + col] = f2bf(o);
                }
            }
        } else {
            const int hh = (col - 1024) >> 6, d = (col - 1024) & 63;
            #pragma unroll
            for (int mt = 0; mt < 4; ++mt) {
                const int rowb = row0 + wr * 64 + mt * 16 + lg * 4;
                const int bb = rowb >> 11, ss = rowb & (SEQ - 1);
                ushort4 o4;
                o4.x = f2bf(acc[mt][nt][0] + bv);
                o4.y = f2bf(acc[mt][nt][1] + bv);
                o4.z = f2bf(acc[mt][nt][2] + bv);
                o4.w = f2bf(acc[mt][nt][3] + bv);
                *(ushort4*)&vt[((size_t)(bb * NHEADS + hh) * HD + d) * SEQ + ss] = o4;
            }
        }
    }
}

// ---------------------------------------------------------------------------
// Flash attention: 8 waves = 4 q-subtiles x 2 KV-halves, XCD-chunked grid,
// within-wave QK/SM/PV interleave (R6), conflict-free LDS perm (R7).
// ---------------------------------------------------------------------------
#define KBLK 64
#define NKT (1024 / KBLK)

__global__ __launch_bounds__(512, 4)
void attn_mfma(const ushort* __restrict__ qkv, const ushort* __restrict__ vt,
               ushort* __restrict__ ctx)
{
    __shared__ __align__(16) ushort smem[2][2][2][64 * 64];   // [buf][half][K/V] 64 KiB

    const int tid = threadIdx.x;
    const int lane = tid & 63;
    const int l32 = lane & 31, hi = lane >> 5;
    const int w = tid >> 6;
    const int qsub = w & 3, half = w >> 2;

    // XCD swizzle: decode (qt,h,b) from the chunked flat id (qt fastest).
    const int flat = blockIdx.x + 16 * (blockIdx.y + 8 * blockIdx.z);
    const int wg = xcd_swz(flat, 512);
    const int qt = wg & 15, h = (wg >> 4) & 7, b = wg >> 7;

    const int q0 = qt * 128 + qsub * 32;
    const int kbase = half * 1024;

    const size_t seqbase = (size_t)b * SEQ;
    const ushort* Qp = qkv + (seqbase + q0 + l32) * QKVSTR + h * HD;
    const ushort* Kg = qkv + seqbase * QKVSTR + 512 + h * HD;
    const ushort* Vg = vt + (size_t)(b * NHEADS + h) * HD * SEQ;

    bf16x8 qf[4];
    #pragma unroll
    for (int c = 0; c < 4; ++c) qf[c] = *(const bf16x8*)&Qp[c * 16 + hi * 8];

    const int srow = lane >> 3;
    const int sslot  = (lane & 7) ^ srow;        // rows 0-7 of each 16-row group
    const int sslot2 = sslot ^ 1;                // rows 8-15: perm ^= 1 (conflict fix)
    const ushort* pK  = Kg + (size_t)(kbase + qsub * 16 + srow) * QKVSTR + sslot * 8;
    const ushort* pK2 = Kg + (size_t)(kbase + qsub * 16 + 8 + srow) * QKVSTR + sslot2 * 8;
    const ushort* pV  = Vg + (size_t)(qsub * 16 + srow) * SEQ + kbase + sslot * 8;
    const ushort* pV2 = Vg + (size_t)(qsub * 16 + 8 + srow) * SEQ + kbase + sslot2 * 8;

    // read-side permutation: perm(row) = (row&7) ^ ((row>>3)&1)
    const int pswz = (l32 & 7) ^ ((l32 >> 3) & 1);

    f32x16 o0 = {}, o1 = {};
    float l = 0.f;

    auto STAGE = [&](int buf) {
        ushort* dK = &smem[buf][half][0][(qsub * 16) * 64];
        ushort* dV = &smem[buf][half][1][(qsub * 16) * 64];
        gload16(pK,  dK);
        gload16(pK2, dK + 8 * 64);
        gload16(pV,  dV);
        gload16(pV2, dV + 8 * 64);
        pK  += (size_t)KBLK * QKVSTR;
        pK2 += (size_t)KBLK * QKVSTR;
        pV  += KBLK;
        pV2 += KBLK;
    };

    auto COMPUTE = [&](int buf) {
        const ushort* KsH = &smem[buf][half][0][0];
        const ushort* VsH = &smem[buf][half][1][0];

        f32x16 s0 = {}, s1 = {};

        __builtin_amdgcn_s_setprio(1);
        #pragma unroll
        for (int c = 0; c < 4; ++c) {
            const bf16x8 kf0 = *(const bf16x8*)&KsH[l32 * 64 + (((2 * c + hi) ^ pswz) * 8)];
            s0 = __builtin_amdgcn_mfma_f32_32x32x16_bf16(kf0, qf[c], s0, 0, 0, 0);
        }
        __builtin_amdgcn_s_setprio(0);

        #pragma unroll
        for (int c = 0; c < 4; ++c) {
            const bf16x8 kf1 = *(const bf16x8*)&KsH[(32 + l32) * 64 + (((2 * c + hi) ^ pswz) * 8)];
            s1 = __builtin_amdgcn_mfma_f32_32x32x16_bf16(kf1, qf[c], s1, 0, 0, 0);
        }

        float ts = 0.f;
        unsigned wp[16];
        union { unsigned u[4]; bf16x8 v; } pb[4];

        #pragma unroll
        for (int r = 0; r < 16; ++r) { s0[r] = exp2_hw(s0[r]); ts += s0[r]; }
        #pragma unroll
        for (int j = 0; j < 8; ++j) wp[j] = cvt_pk_bf16(s0[2 * j], s0[2 * j + 1]);
        plswap(wp[0], wp[2]);  plswap(wp[1], wp[3]);
        plswap(wp[4], wp[6]);  plswap(wp[5], wp[7]);
        pb[0].u[0] = wp[0]; pb[0].u[1] = wp[1]; pb[0].u[2] = wp[2]; pb[0].u[3] = wp[3];
        pb[1].u[0] = wp[4]; pb[1].u[1] = wp[5]; pb[1].u[2] = wp[6]; pb[1].u[3] = wp[7];

        #pragma unroll
        for (int kg = 0; kg < 2; ++kg) {
            const bf16x8 vf0 = *(const bf16x8*)&VsH[l32 * 64 + (((2 * kg + hi) ^ pswz) * 8)];
            o0 = __builtin_amdgcn_mfma_f32_32x32x16_bf16(vf0, pb[kg].v, o0, 0, 0, 0);
            const bf16x8 vf1 = *(const bf16x8*)&VsH[(32 + l32) * 64 + (((2 * kg + hi) ^ pswz) * 8)];
            o1 = __builtin_amdgcn_mfma_f32_32x32x16_bf16(vf1, pb[kg].v, o1, 0, 0, 0);
        }

        #pragma unroll
        for (int r = 0; r < 16; ++r) { s1[r] = exp2_hw(s1[r]); ts += s1[r]; }
        #pragma unroll
        for (int j = 0; j < 8; ++j) wp[8 + j] = cvt_pk_bf16(s1[2 * j], s1[2 * j + 1]);
        plswap(wp[8], wp[10]);  plswap(wp[9], wp[11]);
        plswap(wp[12], wp[14]); plswap(wp[13], wp[15]);
        pb[2].u[0] = wp[8];  pb[2].u[1] = wp[9];  pb[2].u[2] = wp[10]; pb[2].u[3] = wp[11];
        pb[3].u[0] = wp[12]; pb[3].u[1] = wp[13]; pb[3].u[2] = wp[14]; pb[3].u[3] = wp[15];

        #pragma unroll
        for (int kg = 2; kg < 4; ++kg) {
            const bf16x8 vf0 = *(const bf16x8*)&VsH[l32 * 64 + (((2 * kg + hi) ^ pswz) * 8)];
            o0 = __builtin_amdgcn_mfma_f32_32x32x16_bf16(vf0, pb[kg].v, o0, 0, 0, 0);
            const bf16x8 vf1 = *(const bf16x8*)&VsH[(32 + l32) * 64 + (((2 * kg + hi) ^ pswz) * 8)];
            o1 = __builtin_amdgcn_mfma_f32_32x32x16_bf16(vf1, pb[kg].v, o1, 0, 0, 0);
        }

        l += ts;
    };

    STAGE(0);
    __syncthreads();
    for (int tt = 0; tt < NKT; tt += 2) {
        if (tt + 1 < NKT) STAGE(1);
        COMPUTE(0);
        __syncthreads();
        if (tt + 2 < NKT) STAGE(0);
        COMPUTE(1);
        __syncthreads();
    }

    { float a_ = l, b_ = l; plswapf(a_, b_); l = a_ + b_; }

    // ---- merge the two KV-halves per q-subtile (plain sums) ----
    float* so = (float*)smem;                             // [4][64][33]
    float* sl = (float*)((char*)smem + 4 * 64 * 33 * 4);  // [4][64]
    if (half) {
        float* row = so + (qsub * 64 + lane) * 33;
        #pragma unroll
        for (int r = 0; r < 16; ++r) row[r] = o0[r];
        #pragma unroll
        for (int r = 0; r < 16; ++r) row[16 + r] = o1[r];
        sl[qsub * 64 + lane] = l;
    }
    __syncthreads();
    if (!half) {
        const float lb = sl[qsub * 64 + lane];
        const float* row = so + (qsub * 64 + lane) * 33;
        const float inv = 1.f / (l + lb);

        ushort* dst = ctx + (seqbase + q0 + l32) * D + h * HD;
        #pragma unroll
        for (int g = 0; g < 4; ++g) {
            ushort4 t0, t1;
            t0.x = f2bf((o0[g * 4 + 0] + row[g * 4 + 0]) * inv);
            t0.y = f2bf((o0[g * 4 + 1] + row[g * 4 + 1]) * inv);
            t0.z = f2bf((o0[g * 4 + 2] + row[g * 4 + 2]) * inv);
            t0.w = f2bf((o0[g * 4 + 3] + row[g * 4 + 3]) * inv);
            t1.x = f2bf((o1[g * 4 + 0] + row[16 + g * 4 + 0]) * inv);
            t1.y = f2bf((o1[g * 4 + 1] + row[16 + g * 4 + 1]) * inv);
            t1.z = f2bf((o1[g * 4 + 2] + row[16 + g * 4 + 2]) * inv);
            t1.w = f2bf((o1[g * 4 + 3] + row[16 + g * 4 + 3]) * inv);
            *(ushort4*)&dst[g * 8 + hi * 4]      = t0;
            *(ushort4*)&dst[32 + g * 8 + hi * 4] = t1;
        }
    }
}

// ---------------------------------------------------------------------------
// out = LayerNorm(res + y + bias) * g + beta.  (R8: single y buffer — the
// split-K partial pair is gone.)
// ---------------------------------------------------------------------------
template<int RESBF, int OUTBF>
__global__ __launch_bounds__(256)
void add_ln2(const void* __restrict__ res, const float* __restrict__ y,
             const float* __restrict__ bias,
             const float* __restrict__ g, const float* __restrict__ beta,
             float* __restrict__ outf, ushort* __restrict__ outb)
{
    const int wave = threadIdx.x >> 6, lane = threadIdx.x & 63;
    const size_t row = (size_t)blockIdx.x * 4 + wave;

    float xr[8];
    if (RESBF) {
        const ushort* pr = (const ushort*)res + row * D + lane * 8;
        const ushort4 r0 = *(const ushort4*)pr;
        const ushort4 r1 = *(const ushort4*)(pr + 4);
        xr[0] = bf2f(r0.x); xr[1] = bf2f(r0.y); xr[2] = bf2f(r0.z); xr[3] = bf2f(r0.w);
        xr[4] = bf2f(r1.x); xr[5] = bf2f(r1.y); xr[6] = bf2f(r1.z); xr[7] = bf2f(r1.w);
    } else {
        const float* pr = (const float*)res + row * D + lane * 8;
        const float4 r0 = *(const float4*)pr;
        const float4 r1 = *(const float4*)(pr + 4);
        xr[0] = r0.x; xr[1] = r0.y; xr[2] = r0.z; xr[3] = r0.w;
        xr[4] = r1.x; xr[5] = r1.y; xr[6] = r1.z; xr[7] = r1.w;
    }

    const float* p0 = &y[row * D + lane * 8];
    const float4 c0 = *(const float4*)p0;
    const float4 c1 = *(const float4*)(p0 + 4);
    const float4 bb0 = *(const float4*)&bias[lane * 8];
    const float4 bb1 = *(const float4*)&bias[lane * 8 + 4];

    float x[8];
    x[0] = xr[0] + c0.x + bb0.x; x[1] = xr[1] + c0.y + bb0.y;
    x[2] = xr[2] + c0.z + bb0.z; x[3] = xr[3] + c0.w + bb0.w;
    x[4] = xr[4] + c1.x + bb1.x; x[5] = xr[5] + c1.y + bb1.y;
    x[6] = xr[6] + c1.z + bb1.z; x[7] = xr[7] + c1.w + bb1.w;

    float sum = 0.f;
    #pragma unroll
    for (int i = 0; i < 8; ++i) sum += x[i];
    #pragma unroll
    for (int off = 32; off >= 1; off >>= 1) sum += __shfl_xor(sum, off);
    const float mu = sum * (1.0f / D);

    float vsum = 0.f;
    #pragma unroll
    for (int i = 0; i < 8; ++i) { const float dxe = x[i] - mu; vsum += dxe * dxe; }
    #pragma unroll
    for (int off = 32; off >= 1; off >>= 1) vsum += __shfl_xor(vsum, off);
    const float rs = rsqrtf(vsum * (1.0f / D) + 1e-5f);

    const float4 g0  = *(const float4*)&g[lane * 8];
    const float4 g1v = *(const float4*)&g[lane * 8 + 4];
    const float4 be0 = *(const float4*)&beta[lane * 8];
    const float4 be1 = *(const float4*)&beta[lane * 8 + 4];

    float o[8];
    o[0] = (x[0] - mu) * rs * g0.x  + be0.x;
    o[1] = (x[1] - mu) * rs * g0.y  + be0.y;
    o[2] = (x[2] - mu) * rs * g0.z  + be0.z;
    o[3] = (x[3] - mu) * rs * g0.w  + be0.w;
    o[4] = (x[4] - mu) * rs * g1v.x + be1.x;
    o[5] = (x[5] - mu) * rs * g1v.y + be1.y;
    o[6] = (x[6] - mu) * rs * g1v.z + be1.z;
    o[7] = (x[7] - mu) * rs * g1v.w + be1.w;

    if (OUTBF) {
        ushort4 lo, hi;
        lo.x = f2bf(o[0]); lo.y = f2bf(o[1]); lo.z = f2bf(o[2]); lo.w = f2bf(o[3]);
        hi.x = f2bf(o[4]); hi.y = f2bf(o[5]); hi.z = f2bf(o[6]); hi.w = f2bf(o[7]);
        ushort* pq = &outb[row * D + lane * 8];
        *(ushort4*)pq       = lo;
        *(ushort4*)(pq + 4) = hi;
    } else {
        float* po = &outf[row * D + lane * 8];
        *(float4*)po       = *(float4*)&o[0];
        *(float4*)(po + 4) = *(float4*)&o[4];
    }
}

// ---------------------------------------------------------------------------
// Fused prologue: x cast (blocks 0..2047), weight transposes (2048..5119),
// bias concat (5120..5125).
// ---------------------------------------------------------------------------
__global__ __launch_bounds__(256)
void prep(const float* __restrict__ x, ushort* __restrict__ x_bf,
          const float* __restrict__ wq, const float* __restrict__ wk,
          const float* __restrict__ wv, const float* __restrict__ wo,
          const float* __restrict__ w_up, const float* __restrict__ w_down,
          ushort* __restrict__ Wt_qkv, ushort* __restrict__ Wt_o,
          ushort* __restrict__ Wt_up, ushort* __restrict__ Wt_down,
          const float* __restrict__ bq, const float* __restrict__ bk,
          const float* __restrict__ bv, float* __restrict__ b_qkv)
{
    const int bid = blockIdx.x;
    const int tid = threadIdx.x;

    if (bid < 2048) {
        const int i = bid * 256 + tid;
        const float4 a = *(const float4*)&x[(size_t)i * 8];
        const float4 b = *(const float4*)&x[(size_t)i * 8 + 4];
        ushort4 lo, hi;
        lo.x = f2bf(a.x); lo.y = f2bf(a.y); lo.z = f2bf(a.z); lo.w = f2bf(a.w);
        hi.x = f2bf(b.x); hi.y = f2bf(b.y); hi.z = f2bf(b.z); hi.w = f2bf(b.w);
        *(ushort4*)&x_bf[(size_t)i * 8]     = lo;
        *(ushort4*)&x_bf[(size_t)i * 8 + 4] = hi;
        return;
    }

    if (bid < 5120) {
        __shared__ float t[32][33];
        const int j = bid - 2048;
        const float* W; ushort* Wt; int N, stride, tI;
        if (j < 256)       { W = wq;     Wt = Wt_qkv;              N = 512;  stride = 512;  tI = j; }
        else if (j < 512)  { W = wk;     Wt = Wt_qkv + 512 * 512;  N = 512;  stride = 512;  tI = j - 256; }
        else if (j < 768)  { W = wv;     Wt = Wt_qkv + 1024 * 512; N = 512;  stride = 512;  tI = j - 512; }
        else if (j < 1024) { W = wo;     Wt = Wt_o;                N = 512;  stride = 512;  tI = j - 768; }
        else if (j < 2048) { W = w_up;   Wt = Wt_up;               N = 2048; stride = 512;  tI = j - 1024; }
        else               { W = w_down; Wt = Wt_down;             N = 512;  stride = 2048; tI = j - 2048; }
        const int ntn = N >> 5;
        const int n0 = (tI % ntn) * 32, k0 = (tI / ntn) * 32;
        const int r = tid >> 5, c = tid & 31;
        #pragma unroll
        for (int i = 0; i < 4; ++i)
            t[r + i * 8][c] = W[(size_t)(k0 + r + i * 8) * N + n0 + c];
        __syncthreads();
        #pragma unroll
        for (int i = 0; i < 4; ++i)
            Wt[(size_t)(n0 + r + i * 8) * stride + k0 + c] = f2bf(t[c][r + i * 8]);
        return;
    }

    const int i = (bid - 5120) * 256 + tid;
    if (i < 1536)
        b_qkv[i] = (i < 512) ? bq[i] : (i < 1024 ? bk[i - 512] : bv[i - 1024]);
}

// ---------------------------------------------------------------------------
extern "C" void kernel_launch(void* const* d_in, const int* in_sizes, int n_in,
                              void* d_out, int out_size, void* d_ws, size_t ws_size,
                              hipStream_t stream)
{
    const float* x      = (const float*)d_in[0];
    const float* wq     = (const float*)d_in[1];
    const float* bq     = (const float*)d_in[2];
    const float* wk     = (const float*)d_in[3];
    const float* bk     = (const float*)d_in[4];
    const float* wv     = (const float*)d_in[5];
    const float* bv     = (const float*)d_in[6];
    const float* wo     = (const float*)d_in[7];
    const float* bo     = (const float*)d_in[8];
    const float* w_up   = (const float*)d_in[9];
    const float* b_up   = (const float*)d_in[10];
    const float* w_down = (const float*)d_in[11];
    const float* b_down = (const float*)d_in[12];
    const float* g1     = (const float*)d_in[13];
    const float* beta1  = (const float*)d_in[14];
    const float* g2     = (const float*)d_in[15];
    const float* beta2  = (const float*)d_in[16];
    float* out = (float*)d_out;

    // workspace layout (MiB offsets); all lifetimes verified, peak 96 MiB.
    char* wsb = (char*)d_ws;
    #define WS(ofs_mb) (wsb + ((size_t)(ofs_mb) << 20))
    ushort* Wt_qkv  = (ushort*)WS(0);    // [0,2)   live->QKV gemm
    ushort* Wt_o    = (ushort*)WS(2);    // [2,3)   live->O gemm
    ushort* Wt_up   = (ushort*)WS(3);    // [3,5)   live->up gemm
    ushort* Wt_down = (ushort*)WS(5);    // [5,7)   live->down gemm
    float*  b_qkv   = (float*) WS(7);    // [7,8)
    ushort* x_bf    = (ushort*)WS(8);    // [8,16)  live->QKV gemm
    ushort* qkv_bf  = (ushort*)WS(16);   // [16,40) live->attn
    ushort* vt_bf   = (ushort*)WS(40);   // [40,48) live->attn
    ushort* ctx_bf  = (ushort*)WS(48);   // [48,56) live->O gemm
    float*  y1      = (float*) WS(8);    // [8,24)  O out f32 (x_bf/qkv dead)
    ushort* x1_bf   = (ushort*)WS(40);   // [40,48) ln1 out (vt dead); residual for ln2
    ushort* h_bf    = (ushort*)WS(8);    // [8,40)  up out (y1 dead after ln1)
    float*  y2      = (float*) WS(64);   // [64,80) down out f32
    #undef WS

    const dim3 blk(256), blk8(512);

    prep<<<dim3(5126), blk, 0, stream>>>(x, x_bf, wq, wk, wv, wo, w_up, w_down,
                                         Wt_qkv, Wt_o, Wt_up, Wt_down,
                                         bq, bk, bv, b_qkv);

    gemm_qkv8<<<dim3(12, 64), blk8, 0, stream>>>(x_bf, Wt_qkv, b_qkv, qkv_bf, vt_bf);

    attn_mfma<<<dim3(SEQ / 128, NHEADS, BATCH), blk8, 0, stream>>>(qkv_bf, vt_bf, ctx_bf);

    // O-proj: 128x64 tiles, no split-K -> single f32 y1; bias folded into ln1
    gemm_n64<<<dim3(8, 64), blk8, 0, stream>>>(ctx_bf, Wt_o, y1, 512, 512);
    add_ln2<0, 1><<<dim3(MROWS / 4), blk, 0, stream>>>(x, y1, bo, g1, beta1, nullptr, x1_bf);

    // FFN up + GELU -> bf16 h
    gemm_mfma8<1, 1><<<dim3(16, 64), blk8, 0, stream>>>(x1_bf, Wt_up, b_up, h_bf, MROWS, 2048, 512);
    // down: 128x64 tiles, no split-K -> single f32 y2; bias folded into ln2
    gemm_n64<<<dim3(8, 64), blk8, 0, stream>>>(h_bf, Wt_down, y2, 512, 2048);
    add_ln2<1, 0><<<dim3(MROWS / 4), blk, 0, stream>>>(x1_bf, y2, b_down, g2, beta2, out, nullptr);
}